// Round 5
// baseline (195.213 us; speedup 1.0000x reference)
//
#include <hip/hip_runtime.h>
#include <math.h>

// SSIM-with-logits fused kernel for MI355X (gfx950). Round 5.
// R4 post-mortem: pipeline+pk-math worked (505->89us, no spill, VALUBusy 59%)
// but occupancy 18.7%: 47.6KB double buffer capped LDS at 3 blocks/CU and the
// 512-block grid supplied only 2/CU. Inputs are L3-resident (FETCH~0 on
// replays) => pure issue/latency problem. R5: single 23.6KB LDS buffer
// (2 barriers/group, register prefetch still hides global latency) and
// TILE_H 64 => 1024 blocks = 4 blocks/CU (VGPR cap: 512/112 = 4 waves/SIMD).

typedef __attribute__((ext_vector_type(2))) float f2;

#define H_IMG 1024
#define W_IMG 1024
#define N_IMG 16
#define TILE_W 256
#define TILE_H 64
#define PADR 5
#define LDS_S2 268  // f2 cells per staged row (>= 266)

// Normalized 1D Gaussian, WS=11, sigma=1.5 (absmax 0.0 in R1-R4)
constexpr float GW[11] = {
    0.00102838f, 0.00759877f, 0.03600077f, 0.10936069f, 0.21300553f,
    0.26601172f,
    0.21300553f, 0.10936069f, 0.03600077f, 0.00759877f, 0.00102838f};

__device__ __forceinline__ int reflect_i(int i, int n) {
    i = (i < 0) ? -i : i;
    i = (i >= n) ? (2 * n - 2 - i) : i;
    return i;
}

__device__ __forceinline__ float fast_sigmoid(float x) {
    return __builtin_amdgcn_rcpf(1.0f + __expf(-x));
}

__device__ __forceinline__ void ssim_emit(
    f2 mu, f2 sq, float e12, float& loss_sum)
{
    const float mu1 = mu.x, mu2 = mu.y;
    const float mu1s = mu1 * mu1;
    const float mu2s = mu2 * mu2;
    const float mu12 = mu1 * mu2;
    const float s1  = sq.x - mu1s;
    const float s2  = sq.y - mu2s;
    const float s12 = e12  - mu12;
    const float C1 = 1e-4f, C2 = 9e-4f;
    const float num = (2.0f * mu12 + C1) * (2.0f * s12 + C2);
    const float den = (mu1s + mu2s + C1) * (s1 + s2 + C2);
    float l = 1.0f - num * __builtin_amdgcn_rcpf(den);
    l = fminf(fmaxf(l, 0.0f), 1.0f) * 0.5f;
    loss_sum += l;
}

// Issue global loads for NR rows of group at base gb into prefetch registers.
template<int NR>
__device__ __forceinline__ void load_group(
    const float* __restrict__ A, const float* __restrict__ B,
    int y_start, int gb, int c0, int c1, int tid,
    float (&pa)[11], float (&pb)[11], float (&pa2)[11], float (&pb2)[11])
{
#pragma unroll
    for (int r = 0; r < NR; ++r) {
        const int yy = reflect_i(y_start + gb + r, H_IMG);
        const size_t ro = (size_t)yy * W_IMG;
        pa[r] = A[ro + c0];
        pb[r] = B[ro + c0];
        if (tid < 2 * PADR) {
            pa2[r] = A[ro + c1];
            pb2[r] = B[ro + c1];
        }
    }
}

// Sigmoid + write NR prefetched rows into the LDS buffer.
template<int NR>
__device__ __forceinline__ void write_group(
    f2 (*__restrict__ buf)[LDS_S2], int tid,
    const float (&pa)[11], const float (&pb)[11],
    const float (&pa2)[11], const float (&pb2)[11])
{
#pragma unroll
    for (int r = 0; r < NR; ++r) {
        buf[r][tid] = (f2){fast_sigmoid(pa[r]), pb[r]};
        if (tid < 2 * PADR)
            buf[r][TILE_W + tid] = (f2){fast_sigmoid(pa2[r]), pb2[r]};
    }
}

// Process NR staged rows. Group base must be == 0 mod 11 so the mod-11 slot
// indices fold to compile-time constants (validated R2-R4, absmax 0.0).
// GUARD: first group (edge); only r==10 completes an output row.
template<int NR, bool GUARD>
__device__ __forceinline__ void process_group(
    const f2 (*__restrict__ buf)[LDS_S2], int tid,
    f2 (&vAB)[11], f2 (&vSQ)[11], float (&vX)[11], float& loss_sum)
{
#pragma unroll
    for (int r = 0; r < NR; ++r) {
        // ---- horizontal 11-tap, packed (a,b)/(aa,bb) + scalar ab ----
        f2 hAB = (f2)(0.0f), hSQ = (f2)(0.0f);
        float hab = 0.0f;
#pragma unroll
        for (int k = 0; k < 11; ++k) {
            const f2 v   = buf[r][tid + k];
            const f2 wa2 = ((f2)(GW[k])) * v;         // (GW*a, GW*b)
            hAB += wa2;
            hSQ  = __builtin_elementwise_fma(wa2, v, hSQ);
            hab  = fmaf(wa2.x, v.y, hab);
        }
        // ---- vertical scatter into mod-11 slots ----
#pragma unroll
        for (int j = 0; j < 11; ++j) {
            if (!(GUARD && j > r)) {
                const int s = (r - j + 22) % 11;
                const f2 w2 = (f2)(GW[j]);
                vAB[s] = __builtin_elementwise_fma(w2, hAB, vAB[s]);
                vSQ[s] = __builtin_elementwise_fma(w2, hSQ, vSQ[s]);
                vX[s]  = fmaf(GW[j], hab, vX[s]);
            }
        }
        // ---- completion: slot (r+1)%11 finished an output row ----
        if (!GUARD || r == 10) {
            const int s = (r + 1) % 11;
            ssim_emit(vAB[s], vSQ[s], vX[s], loss_sum);
            vAB[s] = (f2)(0.0f); vSQ[s] = (f2)(0.0f); vX[s] = 0.0f;
        }
    }
}

__global__ __launch_bounds__(256, 2) void ssim_main(
    const float* __restrict__ inp, const float* __restrict__ tgt,
    float* __restrict__ out)
{
    __shared__ f2 buf[11][LDS_S2];   // single buffer, ~23.6 KB
    __shared__ float red[4];

    const int tid = threadIdx.x;
    const int blk = blockIdx.x;
    const int b   = blk >> 6;           // image 0..15
    const int rem = blk & 63;
    const int cx  = rem & 3;            // column tile 0..3
    const int ry  = rem >> 2;           // row band 0..15
    const int x0  = cx * TILE_W;
    const int y0  = ry * TILE_H;

    const float* __restrict__ A = inp + (size_t)b * (H_IMG * (size_t)W_IMG);
    const float* __restrict__ B = tgt + (size_t)b * (H_IMG * (size_t)W_IMG);

    const int c0 = reflect_i(x0 - PADR + tid, W_IMG);
    const int c1 = (tid < 2 * PADR) ? reflect_i(x0 + TILE_W - PADR + tid, W_IMG) : 0;

    f2 vAB[11], vSQ[11];
    float vX[11];
#pragma unroll
    for (int j = 0; j < 11; ++j) {
        vAB[j] = (f2)(0.0f); vSQ[j] = (f2)(0.0f); vX[j] = 0.0f;
    }
    float pa[11], pb[11], pa2[11], pb2[11];
    float loss_sum = 0.0f;

    const int y_start = y0 - PADR;  // 74 input rows: 6 groups of 11 + 8

    // prologue: stage group 0, prefetch group 1, process group 0
    load_group<11>(A, B, y_start, 0, c0, c1, tid, pa, pb, pa2, pb2);
    write_group<11>(buf, tid, pa, pb, pa2, pb2);
    load_group<11>(A, B, y_start, 11, c0, c1, tid, pa, pb, pa2, pb2);
    __syncthreads();
    process_group<11, true>(buf, tid, vAB, vSQ, vX, loss_sum);

    // main loop: groups 1..5; prefetched loads fly under process of g
#pragma unroll 1
    for (int g = 1; g <= 5; ++g) {
        __syncthreads();                               // reads of g-1 done
        write_group<11>(buf, tid, pa, pb, pa2, pb2);   // group g
        if (g < 5)
            load_group<11>(A, B, y_start, (g + 1) * 11, c0, c1, tid, pa, pb, pa2, pb2);
        else
            load_group<8>(A, B, y_start, 66, c0, c1, tid, pa, pb, pa2, pb2);
        __syncthreads();
        process_group<11, false>(buf, tid, vAB, vSQ, vX, loss_sum);
    }

    // tail: rows 66..73 (66 % 11 == 0 keeps slot math constant)
    __syncthreads();
    write_group<8>(buf, tid, pa, pb, pa2, pb2);
    __syncthreads();
    process_group<8, false>(buf, tid, vAB, vSQ, vX, loss_sum);

    // ---- reduction: wave64 shuffle -> LDS across 4 waves -> atomicAdd ----
#pragma unroll
    for (int off = 32; off > 0; off >>= 1)
        loss_sum += __shfl_down(loss_sum, off, 64);
    const int wave = tid >> 6;
    if ((tid & 63) == 0) red[wave] = loss_sum;
    __syncthreads();
    if (tid == 0) {
        const float s = red[0] + red[1] + red[2] + red[3];
        atomicAdd(out, s * (1.0f / ((float)N_IMG * H_IMG * W_IMG)));
    }
}

extern "C" void kernel_launch(void* const* d_in, const int* in_sizes, int n_in,
                              void* d_out, int out_size, void* d_ws, size_t ws_size,
                              hipStream_t stream) {
    const float* inp = (const float*)d_in[0];
    const float* tgt = (const float*)d_in[1];
    float* out = (float*)d_out;

    // d_out is poisoned 0xAA before every launch; zero it for the atomic sum.
    hipMemsetAsync(out, 0, sizeof(float), stream);

    const int grid = N_IMG * 4 * (H_IMG / TILE_H);  // 1024 blocks, 4/CU
    ssim_main<<<grid, 256, 0, stream>>>(inp, tgt, out);
}